// Round 10
// baseline (265.745 us; speedup 1.0000x reference)
//
#include <hip/hip_runtime.h>
#include <stdint.h>

#define N_TOT 16384
#define LNEI  32
#define DM    256
#define NH    8
#define DH    32
#define DFF   1024

typedef __attribute__((ext_vector_type(8))) short  short8;
typedef __attribute__((ext_vector_type(4))) float  floatx4;
typedef __attribute__((ext_vector_type(2))) float  float2_t;
typedef __attribute__((ext_vector_type(4))) int    intx4;
typedef __attribute__((ext_vector_type(4))) unsigned short ushort4_t;
typedef __attribute__((ext_vector_type(4))) unsigned int uint4_t;

#if defined(__has_builtin)
#if __has_builtin(__builtin_amdgcn_fdot2_f32_bf16)
#define HAS_DOT2 1
#endif
#endif
#ifndef HAS_DOT2
#define HAS_DOT2 0
#endif

#if HAS_DOT2
typedef __attribute__((ext_vector_type(2))) __bf16 bf16x2_t;
#endif

static __device__ __forceinline__ float b2f(unsigned short u) {
  union { unsigned int u; float f; } x; x.u = ((unsigned int)u) << 16; return x.f;
}
static __device__ __forceinline__ unsigned short f2b(float f) {
  union { float f; unsigned int u; } x; x.f = f;
  unsigned int r = x.u + 0x7fffu + ((x.u >> 16) & 1u);
  return (unsigned short)(r >> 16);
}
static __device__ __forceinline__ float lo16(unsigned int d) {
  union { unsigned int u; float f; } x; x.u = d << 16; return x.f;
}
static __device__ __forceinline__ float hi16(unsigned int d) {
  union { unsigned int u; float f; } x; x.u = d & 0xffff0000u; return x.f;
}

// -------- conversion pass: f32 -> bf16 into ws (strided dst, src=null -> 0) --
#define NSEG 11
struct Seg { const float* src; unsigned short* dst; int cols; int ostride; int ooff; int begin; };
struct SegTable { Seg s[NSEG]; int total; };

__global__ __launch_bounds__(256) void cvt_all(SegTable T, float* biaskv,
                                               const float* bkc, const float* bkp,
                                               const float* bv) {
  int e = (blockIdx.x * 256 + threadIdx.x) * 4;
  if (e >= T.total) {                       // trailing block: bias concat
    int c = e - T.total;
    #pragma unroll
    for (int j = 0; j < 4; ++j, ++c)
      if (c < 512) biaskv[c] = (c < 256) ? (bkc[c] + bkp[c]) : bv[c - 256];
    return;
  }
  int si = 0;
  #pragma unroll
  for (int i = 1; i < NSEG; ++i) if (e >= T.s[i].begin) si = i;
  const Seg s = T.s[si];
  const int le = e - s.begin;
  const int row = le / s.cols;
  const int col = le - row * s.cols;
  floatx4 v = {0.f, 0.f, 0.f, 0.f};
  if (s.src) v = *(const floatx4*)(s.src + le);
  ushort4_t o;
  o.x = f2b(v[0]); o.y = f2b(v[1]); o.z = f2b(v[2]); o.w = f2b(v[3]);
  *(ushort4_t*)(s.dst + (size_t)row * s.ostride + s.ooff + col) = o;
}

static __device__ __forceinline__ void gl_lds16(const unsigned short* g, unsigned short* l) {
  __builtin_amdgcn_global_load_lds(
      (const __attribute__((address_space(1))) unsigned int*)g,
      (__attribute__((address_space(3))) unsigned int*)l, 16, 0, 0);
}

// XCD-chunk swizzle: HW round-robins consecutive blockIdx across the 8 XCDs;
// (bid&7)*chunk + bid>>3 gives each XCD a CONTIGUOUS chunk of flat ids.
static __device__ __forceinline__ int xcd_swz(int bid, int nb) {
  return (bid & 7) * (nb >> 3) + (bid >> 3);
}

// -------- tiled bf16 GEMM body: C = A @ W^T + bias, opt ReLU ----------------
// BM=128, BK=32x2 per barrier pair, BN in {64,128}. global_load_lds width=16.
// MFMA 16x16x32; A-frag lane: A[r=l16][k=quad*8..+8]; C/D col=l16, row=quad*4+i.
template<int BN, bool RELU>
static __device__ __forceinline__ void gemm_body(
    const unsigned short* __restrict__ A, const unsigned short* __restrict__ W,
    const float* __restrict__ bias, unsigned short* __restrict__ C,
    int Nd, int K, int lda, int m0, int n0,
    unsigned short* sA, unsigned short* sB)   // sA: 2*128*32, sB: 2*BN*32
{
  constexpr int BM = 128, BK = 32;
  constexpr int MI = (BN == 128) ? 4 : 2;
  constexpr int NI = 4;
  constexpr int sAh = BM * BK, sBh = BN * BK;

  const int w    = threadIdx.x >> 6;
  const int lane = threadIdx.x & 63;
  const int quad = lane >> 4;
  const int l16  = lane & 15;
  const int wrow0 = (BN == 128) ? (w >> 1) * 64 : w * 32;
  const int wcol0 = (BN == 128) ? (w & 1) * 64 : 0;

  const int aflat0 = w * 512 + lane * 8;
  const int ar0 = aflat0 >> 5, ac = aflat0 & 31;

  floatx4 acc[MI][NI] = {};

  for (int k0 = 0; k0 < K; k0 += 2 * BK) {
    __syncthreads();
    #pragma unroll
    for (int half = 0; half < 2; ++half) {
      const int kk = k0 + half * BK;
      #pragma unroll
      for (int c = 0; c < 2; ++c) {
        const int row = ar0 + c * 64;
        gl_lds16(A + (size_t)(m0 + row) * lda + kk + ac, sA + half * sAh + (c * 4 + w) * 512);
      }
      if (BN == 128) {
        #pragma unroll
        for (int c = 0; c < 2; ++c) {
          const int row = ar0 + c * 64;
          gl_lds16(W + (size_t)(n0 + row) * K + kk + ac, sB + half * sBh + (c * 4 + w) * 512);
        }
      } else {
        gl_lds16(W + (size_t)(n0 + ar0) * K + kk + ac, sB + half * sBh + w * 512);
      }
    }
    __syncthreads();

    #pragma unroll
    for (int half = 0; half < 2; ++half) {
      short8 af[MI], bf[NI];
      #pragma unroll
      for (int mi = 0; mi < MI; ++mi)
        af[mi] = *(const short8*)&sA[half * sAh + (wrow0 + mi * 16 + l16) * BK + quad * 8];
      #pragma unroll
      for (int ni = 0; ni < NI; ++ni)
        bf[ni] = *(const short8*)&sB[half * sBh + (wcol0 + ni * 16 + l16) * BK + quad * 8];
      #pragma unroll
      for (int mi = 0; mi < MI; ++mi)
        #pragma unroll
        for (int ni = 0; ni < NI; ++ni)
          acc[mi][ni] = __builtin_amdgcn_mfma_f32_16x16x32_bf16(af[mi], bf[ni], acc[mi][ni], 0, 0, 0);
    }
  }

  #pragma unroll
  for (int ni = 0; ni < NI; ++ni) {
    const int col = n0 + wcol0 + ni * 16 + l16;
    const float bvv = bias[col];
    #pragma unroll
    for (int mi = 0; mi < MI; ++mi) {
      const int row0 = m0 + wrow0 + mi * 16 + quad * 4;
      #pragma unroll
      for (int i = 0; i < 4; ++i) {
        float v = acc[mi][ni][i] + bvv;
        if (RELU) v = fmaxf(v, 0.f);
        C[(size_t)(row0 + i) * Nd + col] = f2b(v);
      }
    }
  }
}

// 1-D grid, XCD-chunk swizzle, y-FASTEST decomposition: consecutive flat ids
// share the same A row-panel -> A re-reads become L2 hits on one XCD instead
// of L3 re-fetches spread over 8 XCDs.
template<int BN, bool RELU, int NY>
__global__ __launch_bounds__(256) void gemm_tile(
    const unsigned short* __restrict__ A, const unsigned short* __restrict__ W,
    const float* __restrict__ bias,
    unsigned short* __restrict__ C, int M, int Nd, int K, int lda)
{
  __shared__ unsigned short sA[2 * 128 * 32];
  __shared__ unsigned short sB[2 * BN * 32];
  const int f  = xcd_swz(blockIdx.x, gridDim.x);
  const int bx = f / NY, by = f % NY;
  gemm_body<BN, RELU>(A, W, bias, C, Nd, K, lda,
                      bx * 128, by * BN, sA, sB);
}

// -------- merged Q-proj + KV-proj: 1024 blocks, swizzled, y-fastest ---------
// yy<4: q = tgt_b @ Wq^T + bq (BN=64); yy>=4: kv = mp_b @ Wkv^T + bkv (BN=128).
// y-fastest: the 8 blocks of one x run on one XCD -> tgt & mp tiles L2-reused.
__global__ __launch_bounds__(256) void gemm_qkv(
    const unsigned short* __restrict__ tgt_b, const unsigned short* __restrict__ Wq_b,
    const float* __restrict__ bq, unsigned short* __restrict__ q_b,
    const unsigned short* __restrict__ mp_b, const unsigned short* __restrict__ Wkv_b,
    const float* __restrict__ bias_kv, unsigned short* __restrict__ kv_b)
{
  __shared__ unsigned short sA[2 * 128 * 32];
  __shared__ unsigned short sB[2 * 128 * 32];
  const int f  = xcd_swz(blockIdx.x, 1024);
  const int bx = f >> 3, yy = f & 7;
  const int m0 = bx * 128;
  if (yy < 4)
    gemm_body<64, false>(tgt_b, Wq_b, bq, q_b, 256, 256, 256,
                         m0, yy * 64, sA, sB);
  else
    gemm_body<128, false>(mp_b, Wkv_b, bias_kv, kv_b, 512, 512, 512,
                          m0, (yy - 4) * 128, sA, sB);
}

// -------- local gather attention: 1 block / query, kv bf16, direct gather ---
// Direct global gathers (best measured; TLP hides L2 latency). Phase A:
// v_dot2_f32_bf16. s_goff: byte offset, or -1 for padded neighbors -> their
// gathers are SKIPPED (Phase A: 8-lane exec mask; Phase B: wave-uniform
// branch, load elided) saving ~10% gather traffic.
// XCD swizzle: n = (blk&7)*2048 + blk>>3 -> per-XCD kv working set ~2MB in L2.
__global__ __launch_bounds__(256) void attn_kernel(
    const unsigned short* __restrict__ q, const unsigned short* __restrict__ kv,
    const int* __restrict__ key_batch_cnt, const int* __restrict__ index_pair,
    const int* __restrict__ index_pair_batch,
    unsigned short* __restrict__ out)
{
  const int n = ((blockIdx.x & 7) << 11) | (blockIdx.x >> 3);
  const int t = threadIdx.x;
  __shared__ unsigned short s_qb[DM];
#if !HAS_DOT2
  __shared__ float s_qf[DM];
#endif
  __shared__ int   s_goff[LNEI];   // byte offset (1024 B/row), -1 = padded
  __shared__ float s_score[NH][LNEI];
  __shared__ float s_prob[NH][LNEI];
  __shared__ float s_out[2][DM];

  const unsigned short qr = q[(size_t)n * DM + t];
  s_qb[t] = qr;
#if !HAS_DOT2
  s_qf[t] = b2f(qr);
#endif
  if (t < 64) {                       // wave 0: offsets + gather indices
    const int b = index_pair_batch[n];              // uniform across wave
    int cnt = (t < 16) ? key_batch_cnt[t] : 0;      // one parallel load
    cnt = (t < b) ? cnt : 0;
    #pragma unroll
    for (int msk = 32; msk >= 1; msk >>= 1) cnt += __shfl_xor(cnt, msk, 64);
    if (t < LNEI) {
      const int ip = index_pair[(size_t)n * LNEI + t];
      s_goff[t] = (ip < 0) ? -1 : ((ip + cnt) << 10);
    }
  }
  __syncthreads();

  // Phase A (coalesced QK): t=(j=t>>3, c8=t&7); masked rows skip all loads
  {
    const int j   = t >> 3;
    const int c8  = t & 7;
    const int off = s_goff[j];
    float part[4] = {0.f, 0.f, 0.f, 0.f};
    if (off >= 0) {
      const char* kbase = (const char*)kv + off;
      #pragma unroll
      for (int i = 0; i < 4; ++i) {
        const int c = c8 + i * 8;                     // 16B chunk, 0..31
        const uint4_t d = *(const uint4_t*)(kbase + c * 16);
#if HAS_DOT2
        union { uint4_t u; bf16x2_t p[4]; } ku, qu;
        ku.u = d;
        qu.u = *(const uint4_t*)&s_qb[c * 8];
        float acc = 0.f;
        #pragma unroll
        for (int r = 0; r < 4; ++r)
          acc = __builtin_amdgcn_fdot2_f32_bf16(ku.p[r], qu.p[r], acc, false);
        part[i] = acc;
#else
        const float* qp = &s_qf[c * 8];
        part[i] = lo16(d.x) * qp[0] + hi16(d.x) * qp[1]
                + lo16(d.y) * qp[2] + hi16(d.y) * qp[3]
                + lo16(d.z) * qp[4] + hi16(d.z) * qp[5]
                + lo16(d.w) * qp[6] + hi16(d.w) * qp[7];
#endif
      }
    }
    #pragma unroll
    for (int i = 0; i < 4; ++i) {                     // all lanes participate
      part[i] += __shfl_xor(part[i], 1, 64);
      part[i] += __shfl_xor(part[i], 2, 64);
    }
    if ((c8 & 3) == 0) {
      const int hodd = c8 >> 2;
      #pragma unroll
      for (int i = 0; i < 4; ++i)
        s_score[2 * i + hodd][j] =
            (off < 0) ? -1e9f : part[i] * 0.17677669529663687f;  // 32^-0.5
    }
  }
  __syncthreads();

  // softmax: t = (h, l)
  {
    const int h = t >> 5;
    const int l = t & 31;
    const float sc = s_score[h][l];
    float mx = sc;
    #pragma unroll
    for (int msk = 16; msk >= 1; msk >>= 1) mx = fmaxf(mx, __shfl_xor(mx, msk, 64));
    const float e = __expf(sc - mx);
    float sm = e;
    #pragma unroll
    for (int msk = 16; msk >= 1; msk >>= 1) sm += __shfl_xor(sm, msk, 64);
    s_prob[h][l] = e / sm;
  }
  __syncthreads();

  // Phase B: t=(jh,h,dh2); masked j skipped (off<0 is wave-uniform per j2)
  {
    const int jh  = t >> 7;
    const int h   = (t >> 4) & 7;
    const int dh2 = t & 15;
    floatx4 p4[4];
    intx4   o4[4];
    #pragma unroll
    for (int r = 0; r < 4; ++r) {
      p4[r] = *(const floatx4*)&s_prob[h][jh * 16 + r * 4];
      o4[r] = *(const intx4*)&s_goff[jh * 16 + r * 4];
    }
    float2_t acc = {0.f, 0.f};
    const char* vbase = (const char*)kv + 512 + h * 64 + dh2 * 4;
    #pragma unroll
    for (int j2 = 0; j2 < 16; ++j2) {
      const int off = o4[j2 >> 2][j2 & 3];
      if (off >= 0) {
        const float p = p4[j2 >> 2][j2 & 3];
        const unsigned int d = *(const unsigned int*)(vbase + off);
        acc = __builtin_elementwise_fma((float2_t){p, p},
                                        (float2_t){lo16(d), hi16(d)}, acc);
      }
    }
    s_out[jh][h * DH + dh2 * 2]     = acc[0];
    s_out[jh][h * DH + dh2 * 2 + 1] = acc[1];
  }
  __syncthreads();

  out[(size_t)n * DM + t] = f2b(s_out[0][t] + s_out[1][t]);
}

// -------- residual + LayerNorm: 1 wave per row, 4 elems/lane, no LDS --------
template<bool IN1F32, bool OUTF32>
__global__ __launch_bounds__(256) void ln_kernel(
    const void* __restrict__ in1, const unsigned short* __restrict__ in2,
    const float* __restrict__ g, const float* __restrict__ b,
    void* __restrict__ out)
{
  const int n    = blockIdx.x * 4 + (threadIdx.x >> 6);
  const int lane = threadIdx.x & 63;
  const int c0   = lane * 4;

  float a[4];
  if (IN1F32) {
    const floatx4 v = *(const floatx4*)((const float*)in1 + (size_t)n * DM + c0);
    a[0] = v[0]; a[1] = v[1]; a[2] = v[2]; a[3] = v[3];
  } else {
    const ushort4_t u = *(const ushort4_t*)((const unsigned short*)in1 + (size_t)n * DM + c0);
    a[0] = b2f(u.x); a[1] = b2f(u.y); a[2] = b2f(u.z); a[3] = b2f(u.w);
  }
  {
    const ushort4_t u = *(const ushort4_t*)(in2 + (size_t)n * DM + c0);
    a[0] += b2f(u.x); a[1] += b2f(u.y); a[2] += b2f(u.z); a[3] += b2f(u.w);
  }

  float s = a[0] + a[1] + a[2] + a[3];
  #pragma unroll
  for (int msk = 32; msk >= 1; msk >>= 1) s += __shfl_xor(s, msk, 64);
  const float mean = s * (1.0f / DM);

  float d[4], s2 = 0.f;
  #pragma unroll
  for (int i = 0; i < 4; ++i) { d[i] = a[i] - mean; s2 += d[i] * d[i]; }
  #pragma unroll
  for (int msk = 32; msk >= 1; msk >>= 1) s2 += __shfl_xor(s2, msk, 64);
  const float r = rsqrtf(s2 * (1.0f / DM) + 1e-5f);

  const floatx4 gv = *(const floatx4*)(g + c0);
  const floatx4 bv = *(const floatx4*)(b + c0);
  if (OUTF32) {
    floatx4 y;
    #pragma unroll
    for (int i = 0; i < 4; ++i) y[i] = d[i] * r * gv[i] + bv[i];
    *((floatx4*)((float*)out + (size_t)n * DM + c0)) = y;
  } else {
    ushort4_t y;
    y.x = f2b(d[0] * r * gv[0] + bv[0]);
    y.y = f2b(d[1] * r * gv[1] + bv[1]);
    y.z = f2b(d[2] * r * gv[2] + bv[2]);
    y.w = f2b(d[3] * r * gv[3] + bv[3]);
    *((ushort4_t*)((unsigned short*)out + (size_t)n * DM + c0)) = y;
  }
}

extern "C" void kernel_launch(void* const* d_in, const int* in_sizes, int n_in,
                              void* d_out, int out_size, void* d_ws, size_t ws_size,
                              hipStream_t stream) {
  const float* tgt  = (const float*)d_in[0];
  const float* mem  = (const float*)d_in[1];
  const float* pos  = (const float*)d_in[2];
  const int* kbc    = (const int*)d_in[3];
  const int* ipair  = (const int*)d_in[4];
  const int* ipb    = (const int*)d_in[5];
  const float* Wq   = (const float*)d_in[6];
  const float* bq   = (const float*)d_in[7];
  const float* Wkc  = (const float*)d_in[8];
  const float* bkc  = (const float*)d_in[9];
  const float* Wkp  = (const float*)d_in[10];
  const float* bkp  = (const float*)d_in[11];
  const float* Wv   = (const float*)d_in[12];
  const float* bvp  = (const float*)d_in[13];
  const float* Wo   = (const float*)d_in[14];
  const float* bo   = (const float*)d_in[15];
  const float* W1   = (const float*)d_in[16];
  const float* b1   = (const float*)d_in[17];
  const float* W2   = (const float*)d_in[18];
  const float* b2   = (const float*)d_in[19];
  const float* g2   = (const float*)d_in[20];
  const float* be2  = (const float*)d_in[21];
  const float* g3   = (const float*)d_in[22];
  const float* be3  = (const float*)d_in[23];

  const size_t NB = (size_t)N_TOT * DM;
  unsigned short* ws = (unsigned short*)d_ws;
  unsigned short* tgt_b = ws;
  unsigned short* ao_b  = ws;
  unsigned short* t2_b  = ws + NB;
  unsigned short* mp_b  = ws + 2 * NB;
  unsigned short* x_b   = ws + 2 * NB;
  unsigned short* ff_b  = ws + 3 * NB;
  unsigned short* q_b   = ws + 4 * NB;
  unsigned short* h1_b  = ws + 4 * NB;
  unsigned short* kv_b  = ws + 5 * NB;
  unsigned short* wgt   = ws + 8 * NB;
  unsigned short* Wq_b  = wgt;
  unsigned short* Wkv_b = wgt + 65536;
  unsigned short* Wo_b  = wgt + 65536 + 262144;
  unsigned short* W1_b  = wgt + 2 * 65536 + 262144;
  unsigned short* W2_b  = wgt + 2 * 65536 + 2 * 262144;
  float* bias_kv = (float*)(wgt + 2 * 65536 + 3 * 262144);

  SegTable T;
  int beg = 0, i = 0;
  auto seg = [&](const float* s, unsigned short* d, int cols, int ostride, int ooff, int nelem) {
    T.s[i].src = s; T.s[i].dst = d; T.s[i].cols = cols;
    T.s[i].ostride = ostride; T.s[i].ooff = ooff; T.s[i].begin = beg;
    beg += nelem; ++i;
  };
  seg(tgt, tgt_b, DM, DM, 0,   (int)NB);
  seg(mem, mp_b,  DM, 512, 0,  (int)NB);
  seg(pos, mp_b,  DM, 512, DM, (int)NB);
  seg(Wq,  Wq_b,  DM, DM, 0,   65536);
  seg(Wkc, Wkv_b, DM, 512, 0,  65536);
  seg(Wkp, Wkv_b, DM, 512, DM, 65536);
  seg(Wv,  Wkv_b + (size_t)256 * 512, DM, 512, 0, 65536);
  seg(nullptr, Wkv_b + (size_t)256 * 512, DM, 512, DM, 65536);
  seg(Wo,  Wo_b,  DM, DM, 0,   65536);
  seg(W1,  W1_b,  DM, DM, 0,   262144);
  seg(W2,  W2_b,  DFF, DFF, 0, 262144);
  T.total = beg;

  dim3 blk(256);
  cvt_all<<<dim3(T.total / 1024 + 1), blk, 0, stream>>>(T, bias_kv, bkc, bkp, bvp);

  gemm_qkv<<<dim3(1024), blk, 0, stream>>>(tgt_b, Wq_b, bq, q_b, mp_b, Wkv_b, bias_kv, kv_b);
  attn_kernel<<<dim3(N_TOT), blk, 0, stream>>>(q_b, kv_b, kbc, ipair, ipb, ao_b);
  gemm_tile<64, false, 4><<<dim3(512), blk, 0, stream>>>(ao_b, Wo_b, bo, t2_b, N_TOT, DM, DM, DM);
  ln_kernel<true, false><<<dim3(N_TOT / 4), blk, 0, stream>>>(tgt, t2_b, g2, be2, x_b);
  gemm_tile<128, true, 8><<<dim3(1024), blk, 0, stream>>>(x_b, W1_b, b1, h1_b, N_TOT, DFF, DM, DM);
  gemm_tile<64, false, 4><<<dim3(512), blk, 0, stream>>>(h1_b, W2_b, b2, ff_b, N_TOT, DM, DFF, DFF);
  ln_kernel<false, true><<<dim3(N_TOT / 4), blk, 0, stream>>>(x_b, ff_b, g3, be3, d_out);
}

// Round 11
// 251.135 us; speedup vs baseline: 1.0582x; 1.0582x over previous
//
#include <hip/hip_runtime.h>
#include <stdint.h>

#define N_TOT 16384
#define LNEI  32
#define DM    256
#define NH    8
#define DH    32
#define DFF   1024

typedef __attribute__((ext_vector_type(8))) short  short8;
typedef __attribute__((ext_vector_type(4))) float  floatx4;
typedef __attribute__((ext_vector_type(2))) float  float2_t;
typedef __attribute__((ext_vector_type(4))) int    intx4;
typedef __attribute__((ext_vector_type(4))) unsigned short ushort4_t;
typedef __attribute__((ext_vector_type(4))) unsigned int uint4_t;

#if defined(__has_builtin)
#if __has_builtin(__builtin_amdgcn_fdot2_f32_bf16)
#define HAS_DOT2 1
#endif
#endif
#ifndef HAS_DOT2
#define HAS_DOT2 0
#endif

#if HAS_DOT2
typedef __attribute__((ext_vector_type(2))) __bf16 bf16x2_t;
#endif

static __device__ __forceinline__ float b2f(unsigned short u) {
  union { unsigned int u; float f; } x; x.u = ((unsigned int)u) << 16; return x.f;
}
static __device__ __forceinline__ unsigned short f2b(float f) {
  union { float f; unsigned int u; } x; x.f = f;
  unsigned int r = x.u + 0x7fffu + ((x.u >> 16) & 1u);
  return (unsigned short)(r >> 16);
}
static __device__ __forceinline__ float lo16(unsigned int d) {
  union { unsigned int u; float f; } x; x.u = d << 16; return x.f;
}
static __device__ __forceinline__ float hi16(unsigned int d) {
  union { unsigned int u; float f; } x; x.u = d & 0xffff0000u; return x.f;
}

// -------- conversion pass: f32 -> bf16 into ws (strided dst, src=null -> 0) --
#define NSEG 11
struct Seg { const float* src; unsigned short* dst; int cols; int ostride; int ooff; int begin; };
struct SegTable { Seg s[NSEG]; int total; };

__global__ __launch_bounds__(256) void cvt_all(SegTable T, float* biaskv,
                                               const float* bkc, const float* bkp,
                                               const float* bv) {
  int e = (blockIdx.x * 256 + threadIdx.x) * 4;
  if (e >= T.total) {                       // trailing block: bias concat
    int c = e - T.total;
    #pragma unroll
    for (int j = 0; j < 4; ++j, ++c)
      if (c < 512) biaskv[c] = (c < 256) ? (bkc[c] + bkp[c]) : bv[c - 256];
    return;
  }
  int si = 0;
  #pragma unroll
  for (int i = 1; i < NSEG; ++i) if (e >= T.s[i].begin) si = i;
  const Seg s = T.s[si];
  const int le = e - s.begin;
  const int row = le / s.cols;
  const int col = le - row * s.cols;
  floatx4 v = {0.f, 0.f, 0.f, 0.f};
  if (s.src) v = *(const floatx4*)(s.src + le);
  ushort4_t o;
  o.x = f2b(v[0]); o.y = f2b(v[1]); o.z = f2b(v[2]); o.w = f2b(v[3]);
  *(ushort4_t*)(s.dst + (size_t)row * s.ostride + s.ooff + col) = o;
}

static __device__ __forceinline__ void gl_lds16(const unsigned short* g, unsigned short* l) {
  __builtin_amdgcn_global_load_lds(
      (const __attribute__((address_space(1))) unsigned int*)g,
      (__attribute__((address_space(3))) unsigned int*)l, 16, 0, 0);
}

// XCD-chunk swizzle: HW round-robins consecutive blockIdx across the 8 XCDs;
// (bid&7)*chunk + bid>>3 gives each XCD a CONTIGUOUS chunk of flat ids.
static __device__ __forceinline__ int xcd_swz(int bid, int nb) {
  return (bid & 7) * (nb >> 3) + (bid >> 3);
}

// -------- tiled bf16 GEMM body: C = A @ W^T + bias, opt ReLU ----------------
// BM=128, BK=32x2 per barrier pair, BN in {64,128}. global_load_lds width=16.
// MFMA 16x16x32; A-frag lane: A[r=l16][k=quad*8..+8]; C/D col=l16, row=quad*4+i.
template<int BN, bool RELU>
static __device__ __forceinline__ void gemm_body(
    const unsigned short* __restrict__ A, const unsigned short* __restrict__ W,
    const float* __restrict__ bias, unsigned short* __restrict__ C,
    int Nd, int K, int lda, int m0, int n0,
    unsigned short* sA, unsigned short* sB)   // sA: 2*128*32, sB: 2*BN*32
{
  constexpr int BM = 128, BK = 32;
  constexpr int MI = (BN == 128) ? 4 : 2;
  constexpr int NI = 4;
  constexpr int sAh = BM * BK, sBh = BN * BK;

  const int w    = threadIdx.x >> 6;
  const int lane = threadIdx.x & 63;
  const int quad = lane >> 4;
  const int l16  = lane & 15;
  const int wrow0 = (BN == 128) ? (w >> 1) * 64 : w * 32;
  const int wcol0 = (BN == 128) ? (w & 1) * 64 : 0;

  const int aflat0 = w * 512 + lane * 8;
  const int ar0 = aflat0 >> 5, ac = aflat0 & 31;

  floatx4 acc[MI][NI] = {};

  for (int k0 = 0; k0 < K; k0 += 2 * BK) {
    __syncthreads();
    #pragma unroll
    for (int half = 0; half < 2; ++half) {
      const int kk = k0 + half * BK;
      #pragma unroll
      for (int c = 0; c < 2; ++c) {
        const int row = ar0 + c * 64;
        gl_lds16(A + (size_t)(m0 + row) * lda + kk + ac, sA + half * sAh + (c * 4 + w) * 512);
      }
      if (BN == 128) {
        #pragma unroll
        for (int c = 0; c < 2; ++c) {
          const int row = ar0 + c * 64;
          gl_lds16(W + (size_t)(n0 + row) * K + kk + ac, sB + half * sBh + (c * 4 + w) * 512);
        }
      } else {
        gl_lds16(W + (size_t)(n0 + ar0) * K + kk + ac, sB + half * sBh + w * 512);
      }
    }
    __syncthreads();

    #pragma unroll
    for (int half = 0; half < 2; ++half) {
      short8 af[MI], bf[NI];
      #pragma unroll
      for (int mi = 0; mi < MI; ++mi)
        af[mi] = *(const short8*)&sA[half * sAh + (wrow0 + mi * 16 + l16) * BK + quad * 8];
      #pragma unroll
      for (int ni = 0; ni < NI; ++ni)
        bf[ni] = *(const short8*)&sB[half * sBh + (wcol0 + ni * 16 + l16) * BK + quad * 8];
      #pragma unroll
      for (int mi = 0; mi < MI; ++mi)
        #pragma unroll
        for (int ni = 0; ni < NI; ++ni)
          acc[mi][ni] = __builtin_amdgcn_mfma_f32_16x16x32_bf16(af[mi], bf[ni], acc[mi][ni], 0, 0, 0);
    }
  }

  #pragma unroll
  for (int ni = 0; ni < NI; ++ni) {
    const int col = n0 + wcol0 + ni * 16 + l16;
    const float bvv = bias[col];
    #pragma unroll
    for (int mi = 0; mi < MI; ++mi) {
      const int row0 = m0 + wrow0 + mi * 16 + quad * 4;
      #pragma unroll
      for (int i = 0; i < 4; ++i) {
        float v = acc[mi][ni][i] + bvv;
        if (RELU) v = fmaxf(v, 0.f);
        C[(size_t)(row0 + i) * Nd + col] = f2b(v);
      }
    }
  }
}

// 1-D grid, XCD-chunk swizzle, y-FASTEST decomposition: consecutive flat ids
// share the same A row-panel -> A re-reads become L2 hits on one XCD instead
// of L3 re-fetches spread over 8 XCDs.
template<int BN, bool RELU, int NY>
__global__ __launch_bounds__(256) void gemm_tile(
    const unsigned short* __restrict__ A, const unsigned short* __restrict__ W,
    const float* __restrict__ bias,
    unsigned short* __restrict__ C, int M, int Nd, int K, int lda)
{
  __shared__ unsigned short sA[2 * 128 * 32];
  __shared__ unsigned short sB[2 * BN * 32];
  const int f  = xcd_swz(blockIdx.x, gridDim.x);
  const int bx = f / NY, by = f % NY;
  gemm_body<BN, RELU>(A, W, bias, C, Nd, K, lda,
                      bx * 128, by * BN, sA, sB);
}

// -------- merged Q-proj + KV-proj: 1024 blocks, swizzled, y-fastest ---------
// yy<4: q = tgt_b @ Wq^T + bq (BN=64); yy>=4: kv = mp_b @ Wkv^T + bkv (BN=128).
// y-fastest: the 8 blocks of one x run on one XCD -> tgt & mp tiles L2-reused.
__global__ __launch_bounds__(256) void gemm_qkv(
    const unsigned short* __restrict__ tgt_b, const unsigned short* __restrict__ Wq_b,
    const float* __restrict__ bq, unsigned short* __restrict__ q_b,
    const unsigned short* __restrict__ mp_b, const unsigned short* __restrict__ Wkv_b,
    const float* __restrict__ bias_kv, unsigned short* __restrict__ kv_b)
{
  __shared__ unsigned short sA[2 * 128 * 32];
  __shared__ unsigned short sB[2 * 128 * 32];
  const int f  = xcd_swz(blockIdx.x, 1024);
  const int bx = f >> 3, yy = f & 7;
  const int m0 = bx * 128;
  if (yy < 4)
    gemm_body<64, false>(tgt_b, Wq_b, bq, q_b, 256, 256, 256,
                         m0, yy * 64, sA, sB);
  else
    gemm_body<128, false>(mp_b, Wkv_b, bias_kv, kv_b, 512, 512, 512,
                          m0, (yy - 4) * 128, sA, sB);
}

// -------- local gather attention: 1 block / query, kv bf16, direct gather ---
// Round-9 form (42 µs measured): UNCONDITIONAL batched gathers (clamped
// offsets), mask applied only at the score write. Guarding the loads was
// measured at +16 µs (round 10) — conditional loads serialize behind the
// branch and lose the TLP latency hiding. Do not re-guard.
// XCD swizzle: n = (blk&7)*2048 + blk>>3 -> per-XCD kv working set ~2MB in L2.
__global__ __launch_bounds__(256) void attn_kernel(
    const unsigned short* __restrict__ q, const unsigned short* __restrict__ kv,
    const int* __restrict__ key_batch_cnt, const int* __restrict__ index_pair,
    const int* __restrict__ index_pair_batch,
    unsigned short* __restrict__ out)
{
  const int n = ((blockIdx.x & 7) << 11) | (blockIdx.x >> 3);
  const int t = threadIdx.x;
  __shared__ unsigned short s_qb[DM];
#if !HAS_DOT2
  __shared__ float s_qf[DM];
#endif
  __shared__ int   s_gidx[LNEI];   // -1 = padded neighbor (mask)
  __shared__ int   s_goff[LNEI];   // clamped byte offset, 1024 B/row
  __shared__ float s_score[NH][LNEI];
  __shared__ float s_prob[NH][LNEI];
  __shared__ float s_out[2][DM];

  const unsigned short qr = q[(size_t)n * DM + t];
  s_qb[t] = qr;
#if !HAS_DOT2
  s_qf[t] = b2f(qr);
#endif
  if (t < 64) {                       // wave 0: offsets + gather indices
    const int b = index_pair_batch[n];              // uniform across wave
    int cnt = (t < 16) ? key_batch_cnt[t] : 0;      // one parallel load
    cnt = (t < b) ? cnt : 0;
    #pragma unroll
    for (int msk = 32; msk >= 1; msk >>= 1) cnt += __shfl_xor(cnt, msk, 64);
    if (t < LNEI) {
      const int ip = index_pair[(size_t)n * LNEI + t];
      const int gi = (ip < 0) ? -1 : (ip + cnt);
      s_gidx[t] = gi;
      s_goff[t] = (gi < 0 ? 0 : gi) << 10;
    }
  }
  __syncthreads();

  // Phase A (coalesced QK): t=(j=t>>3, c8=t&7)
  {
    const int j  = t >> 3;
    const int c8 = t & 7;
    const int g  = s_gidx[j];
    const char* kbase = (const char*)kv + s_goff[j];

    float part[4];
    #pragma unroll
    for (int i = 0; i < 4; ++i) {
      const int c = c8 + i * 8;                       // 16B chunk, 0..31
      const uint4_t d = *(const uint4_t*)(kbase + c * 16);
#if HAS_DOT2
      union { uint4_t u; bf16x2_t p[4]; } ku, qu;
      ku.u = d;
      qu.u = *(const uint4_t*)&s_qb[c * 8];
      float acc = 0.f;
      #pragma unroll
      for (int r = 0; r < 4; ++r)
        acc = __builtin_amdgcn_fdot2_f32_bf16(ku.p[r], qu.p[r], acc, false);
      part[i] = acc;
#else
      const float* qp = &s_qf[c * 8];
      part[i] = lo16(d.x) * qp[0] + hi16(d.x) * qp[1]
              + lo16(d.y) * qp[2] + hi16(d.y) * qp[3]
              + lo16(d.z) * qp[4] + hi16(d.z) * qp[5]
              + lo16(d.w) * qp[6] + hi16(d.w) * qp[7];
#endif
    }
    #pragma unroll
    for (int i = 0; i < 4; ++i) {
      part[i] += __shfl_xor(part[i], 1, 64);
      part[i] += __shfl_xor(part[i], 2, 64);
    }
    if ((c8 & 3) == 0) {
      const int hodd = c8 >> 2;
      #pragma unroll
      for (int i = 0; i < 4; ++i)
        s_score[2 * i + hodd][j] =
            (g < 0) ? -1e9f : part[i] * 0.17677669529663687f;  // 32^-0.5
    }
  }
  __syncthreads();

  // softmax: t = (h, l)
  {
    const int h = t >> 5;
    const int l = t & 31;
    const float sc = s_score[h][l];
    float mx = sc;
    #pragma unroll
    for (int msk = 16; msk >= 1; msk >>= 1) mx = fmaxf(mx, __shfl_xor(mx, msk, 64));
    const float e = __expf(sc - mx);
    float sm = e;
    #pragma unroll
    for (int msk = 16; msk >= 1; msk >>= 1) sm += __shfl_xor(sm, msk, 64);
    s_prob[h][l] = e / sm;
  }
  __syncthreads();

  // Phase B: t=(jh,h,dh2)
  {
    const int jh  = t >> 7;
    const int h   = (t >> 4) & 7;
    const int dh2 = t & 15;
    floatx4 p4[4];
    intx4   o4[4];
    #pragma unroll
    for (int r = 0; r < 4; ++r) {
      p4[r] = *(const floatx4*)&s_prob[h][jh * 16 + r * 4];
      o4[r] = *(const intx4*)&s_goff[jh * 16 + r * 4];
    }
    float2_t acc = {0.f, 0.f};
    const char* vbase = (const char*)kv + 512 + h * 64 + dh2 * 4;
    #pragma unroll
    for (int j2 = 0; j2 < 16; ++j2) {
      const int off = o4[j2 >> 2][j2 & 3];
      const float p = p4[j2 >> 2][j2 & 3];
      const unsigned int d = *(const unsigned int*)(vbase + off);
      acc = __builtin_elementwise_fma((float2_t){p, p},
                                      (float2_t){lo16(d), hi16(d)}, acc);
    }
    s_out[jh][h * DH + dh2 * 2]     = acc[0];
    s_out[jh][h * DH + dh2 * 2 + 1] = acc[1];
  }
  __syncthreads();

  out[(size_t)n * DM + t] = f2b(s_out[0][t] + s_out[1][t]);
}

// -------- residual + LayerNorm: 1 wave per row, 4 elems/lane, no LDS --------
template<bool IN1F32, bool OUTF32>
__global__ __launch_bounds__(256) void ln_kernel(
    const void* __restrict__ in1, const unsigned short* __restrict__ in2,
    const float* __restrict__ g, const float* __restrict__ b,
    void* __restrict__ out)
{
  const int n    = blockIdx.x * 4 + (threadIdx.x >> 6);
  const int lane = threadIdx.x & 63;
  const int c0   = lane * 4;

  float a[4];
  if (IN1F32) {
    const floatx4 v = *(const floatx4*)((const float*)in1 + (size_t)n * DM + c0);
    a[0] = v[0]; a[1] = v[1]; a[2] = v[2]; a[3] = v[3];
  } else {
    const ushort4_t u = *(const ushort4_t*)((const unsigned short*)in1 + (size_t)n * DM + c0);
    a[0] = b2f(u.x); a[1] = b2f(u.y); a[2] = b2f(u.z); a[3] = b2f(u.w);
  }
  {
    const ushort4_t u = *(const ushort4_t*)(in2 + (size_t)n * DM + c0);
    a[0] += b2f(u.x); a[1] += b2f(u.y); a[2] += b2f(u.z); a[3] += b2f(u.w);
  }

  float s = a[0] + a[1] + a[2] + a[3];
  #pragma unroll
  for (int msk = 32; msk >= 1; msk >>= 1) s += __shfl_xor(s, msk, 64);
  const float mean = s * (1.0f / DM);

  float d[4], s2 = 0.f;
  #pragma unroll
  for (int i = 0; i < 4; ++i) { d[i] = a[i] - mean; s2 += d[i] * d[i]; }
  #pragma unroll
  for (int msk = 32; msk >= 1; msk >>= 1) s2 += __shfl_xor(s2, msk, 64);
  const float r = rsqrtf(s2 * (1.0f / DM) + 1e-5f);

  const floatx4 gv = *(const floatx4*)(g + c0);
  const floatx4 bv = *(const floatx4*)(b + c0);
  if (OUTF32) {
    floatx4 y;
    #pragma unroll
    for (int i = 0; i < 4; ++i) y[i] = d[i] * r * gv[i] + bv[i];
    *((floatx4*)((float*)out + (size_t)n * DM + c0)) = y;
  } else {
    ushort4_t y;
    y.x = f2b(d[0] * r * gv[0] + bv[0]);
    y.y = f2b(d[1] * r * gv[1] + bv[1]);
    y.z = f2b(d[2] * r * gv[2] + bv[2]);
    y.w = f2b(d[3] * r * gv[3] + bv[3]);
    *((ushort4_t*)((unsigned short*)out + (size_t)n * DM + c0)) = y;
  }
}

extern "C" void kernel_launch(void* const* d_in, const int* in_sizes, int n_in,
                              void* d_out, int out_size, void* d_ws, size_t ws_size,
                              hipStream_t stream) {
  const float* tgt  = (const float*)d_in[0];
  const float* mem  = (const float*)d_in[1];
  const float* pos  = (const float*)d_in[2];
  const int* kbc    = (const int*)d_in[3];
  const int* ipair  = (const int*)d_in[4];
  const int* ipb    = (const int*)d_in[5];
  const float* Wq   = (const float*)d_in[6];
  const float* bq   = (const float*)d_in[7];
  const float* Wkc  = (const float*)d_in[8];
  const float* bkc  = (const float*)d_in[9];
  const float* Wkp  = (const float*)d_in[10];
  const float* bkp  = (const float*)d_in[11];
  const float* Wv   = (const float*)d_in[12];
  const float* bvp  = (const float*)d_in[13];
  const float* Wo   = (const float*)d_in[14];
  const float* bo   = (const float*)d_in[15];
  const float* W1   = (const float*)d_in[16];
  const float* b1   = (const float*)d_in[17];
  const float* W2   = (const float*)d_in[18];
  const float* b2   = (const float*)d_in[19];
  const float* g2   = (const float*)d_in[20];
  const float* be2  = (const float*)d_in[21];
  const float* g3   = (const float*)d_in[22];
  const float* be3  = (const float*)d_in[23];

  const size_t NB = (size_t)N_TOT * DM;
  unsigned short* ws = (unsigned short*)d_ws;
  unsigned short* tgt_b = ws;
  unsigned short* ao_b  = ws;
  unsigned short* t2_b  = ws + NB;
  unsigned short* mp_b  = ws + 2 * NB;
  unsigned short* x_b   = ws + 2 * NB;
  unsigned short* ff_b  = ws + 3 * NB;
  unsigned short* q_b   = ws + 4 * NB;
  unsigned short* h1_b  = ws + 4 * NB;
  unsigned short* kv_b  = ws + 5 * NB;
  unsigned short* wgt   = ws + 8 * NB;
  unsigned short* Wq_b  = wgt;
  unsigned short* Wkv_b = wgt + 65536;
  unsigned short* Wo_b  = wgt + 65536 + 262144;
  unsigned short* W1_b  = wgt + 2 * 65536 + 262144;
  unsigned short* W2_b  = wgt + 2 * 65536 + 2 * 262144;
  float* bias_kv = (float*)(wgt + 2 * 65536 + 3 * 262144);

  SegTable T;
  int beg = 0, i = 0;
  auto seg = [&](const float* s, unsigned short* d, int cols, int ostride, int ooff, int nelem) {
    T.s[i].src = s; T.s[i].dst = d; T.s[i].cols = cols;
    T.s[i].ostride = ostride; T.s[i].ooff = ooff; T.s[i].begin = beg;
    beg += nelem; ++i;
  };
  seg(tgt, tgt_b, DM, DM, 0,   (int)NB);
  seg(mem, mp_b,  DM, 512, 0,  (int)NB);
  seg(pos, mp_b,  DM, 512, DM, (int)NB);
  seg(Wq,  Wq_b,  DM, DM, 0,   65536);
  seg(Wkc, Wkv_b, DM, 512, 0,  65536);
  seg(Wkp, Wkv_b, DM, 512, DM, 65536);
  seg(Wv,  Wkv_b + (size_t)256 * 512, DM, 512, 0, 65536);
  seg(nullptr, Wkv_b + (size_t)256 * 512, DM, 512, DM, 65536);
  seg(Wo,  Wo_b,  DM, DM, 0,   65536);
  seg(W1,  W1_b,  DM, DM, 0,   262144);
  seg(W2,  W2_b,  DFF, DFF, 0, 262144);
  T.total = beg;

  dim3 blk(256);
  cvt_all<<<dim3(T.total / 1024 + 1), blk, 0, stream>>>(T, bias_kv, bkc, bkp, bvp);

  gemm_qkv<<<dim3(1024), blk, 0, stream>>>(tgt_b, Wq_b, bq, q_b, mp_b, Wkv_b, bias_kv, kv_b);
  attn_kernel<<<dim3(N_TOT), blk, 0, stream>>>(q_b, kv_b, kbc, ipair, ipb, ao_b);
  gemm_tile<64, false, 4><<<dim3(512), blk, 0, stream>>>(ao_b, Wo_b, bo, t2_b, N_TOT, DM, DM, DM);
  ln_kernel<true, false><<<dim3(N_TOT / 4), blk, 0, stream>>>(tgt, t2_b, g2, be2, x_b);
  gemm_tile<128, true, 8><<<dim3(1024), blk, 0, stream>>>(x_b, W1_b, b1, h1_b, N_TOT, DFF, DM, DM);
  gemm_tile<64, false, 4><<<dim3(512), blk, 0, stream>>>(h1_b, W2_b, b2, ff_b, N_TOT, DM, DFF, DFF);
  ln_kernel<false, true><<<dim3(N_TOT / 4), blk, 0, stream>>>(x_b, ff_b, g3, be3, d_out);
}

// Round 12
// 248.478 us; speedup vs baseline: 1.0695x; 1.0107x over previous
//
#include <hip/hip_runtime.h>
#include <stdint.h>

#define N_TOT 16384
#define LNEI  32
#define DM    256
#define NH    8
#define DH    32
#define DFF   1024

typedef __attribute__((ext_vector_type(8))) short  short8;
typedef __attribute__((ext_vector_type(4))) float  floatx4;
typedef __attribute__((ext_vector_type(2))) float  float2_t;
typedef __attribute__((ext_vector_type(4))) int    intx4;
typedef __attribute__((ext_vector_type(4))) unsigned short ushort4_t;
typedef __attribute__((ext_vector_type(4))) unsigned int uint4_t;

#if defined(__has_builtin)
#if __has_builtin(__builtin_amdgcn_fdot2_f32_bf16)
#define HAS_DOT2 1
#endif
#endif
#ifndef HAS_DOT2
#define HAS_DOT2 0
#endif

#if HAS_DOT2
typedef __attribute__((ext_vector_type(2))) __bf16 bf16x2_t;
#endif

static __device__ __forceinline__ float b2f(unsigned short u) {
  union { unsigned int u; float f; } x; x.u = ((unsigned int)u) << 16; return x.f;
}
static __device__ __forceinline__ unsigned short f2b(float f) {
  union { float f; unsigned int u; } x; x.f = f;
  unsigned int r = x.u + 0x7fffu + ((x.u >> 16) & 1u);
  return (unsigned short)(r >> 16);
}
static __device__ __forceinline__ float lo16(unsigned int d) {
  union { unsigned int u; float f; } x; x.u = d << 16; return x.f;
}
static __device__ __forceinline__ float hi16(unsigned int d) {
  union { unsigned int u; float f; } x; x.u = d & 0xffff0000u; return x.f;
}

// -------- conversion pass: f32 -> bf16 into ws (strided dst, src=null -> 0) --
#define NSEG 11
struct Seg { const float* src; unsigned short* dst; int cols; int ostride; int ooff; int begin; };
struct SegTable { Seg s[NSEG]; int total; };

__global__ __launch_bounds__(256) void cvt_all(SegTable T, float* biaskv,
                                               const float* bkc, const float* bkp,
                                               const float* bv) {
  int e = (blockIdx.x * 256 + threadIdx.x) * 4;
  if (e >= T.total) {                       // trailing block: bias concat
    int c = e - T.total;
    #pragma unroll
    for (int j = 0; j < 4; ++j, ++c)
      if (c < 512) biaskv[c] = (c < 256) ? (bkc[c] + bkp[c]) : bv[c - 256];
    return;
  }
  int si = 0;
  #pragma unroll
  for (int i = 1; i < NSEG; ++i) if (e >= T.s[i].begin) si = i;
  const Seg s = T.s[si];
  const int le = e - s.begin;
  const int row = le / s.cols;
  const int col = le - row * s.cols;
  floatx4 v = {0.f, 0.f, 0.f, 0.f};
  if (s.src) v = *(const floatx4*)(s.src + le);
  ushort4_t o;
  o.x = f2b(v[0]); o.y = f2b(v[1]); o.z = f2b(v[2]); o.w = f2b(v[3]);
  *(ushort4_t*)(s.dst + (size_t)row * s.ostride + s.ooff + col) = o;
}

static __device__ __forceinline__ void gl_lds16(const unsigned short* g, unsigned short* l) {
  __builtin_amdgcn_global_load_lds(
      (const __attribute__((address_space(1))) unsigned int*)g,
      (__attribute__((address_space(3))) unsigned int*)l, 16, 0, 0);
}

// XCD-chunk swizzle: HW round-robins consecutive blockIdx across the 8 XCDs;
// (bid&7)*chunk + bid>>3 gives each XCD a CONTIGUOUS chunk of flat ids.
static __device__ __forceinline__ int xcd_swz(int bid, int nb) {
  return (bid & 7) * (nb >> 3) + (bid >> 3);
}

// -------- tiled bf16 GEMM body: C = A @ W^T + bias, opt ReLU ----------------
// BM=128, BK=32x2 per barrier pair, BN in {64,128}. global_load_lds width=16.
// MFMA 16x16x32; A-frag lane: A[r=l16][k=quad*8..+8]; C/D col=l16, row=quad*4+i.
template<int BN, bool RELU>
static __device__ __forceinline__ void gemm_body(
    const unsigned short* __restrict__ A, const unsigned short* __restrict__ W,
    const float* __restrict__ bias, unsigned short* __restrict__ C,
    int Nd, int K, int lda, int m0, int n0,
    unsigned short* sA, unsigned short* sB)   // sA: 2*128*32, sB: 2*BN*32
{
  constexpr int BM = 128, BK = 32;
  constexpr int MI = (BN == 128) ? 4 : 2;
  constexpr int NI = 4;
  constexpr int sAh = BM * BK, sBh = BN * BK;

  const int w    = threadIdx.x >> 6;
  const int lane = threadIdx.x & 63;
  const int quad = lane >> 4;
  const int l16  = lane & 15;
  const int wrow0 = (BN == 128) ? (w >> 1) * 64 : w * 32;
  const int wcol0 = (BN == 128) ? (w & 1) * 64 : 0;

  const int aflat0 = w * 512 + lane * 8;
  const int ar0 = aflat0 >> 5, ac = aflat0 & 31;

  floatx4 acc[MI][NI] = {};

  for (int k0 = 0; k0 < K; k0 += 2 * BK) {
    __syncthreads();
    #pragma unroll
    for (int half = 0; half < 2; ++half) {
      const int kk = k0 + half * BK;
      #pragma unroll
      for (int c = 0; c < 2; ++c) {
        const int row = ar0 + c * 64;
        gl_lds16(A + (size_t)(m0 + row) * lda + kk + ac, sA + half * sAh + (c * 4 + w) * 512);
      }
      if (BN == 128) {
        #pragma unroll
        for (int c = 0; c < 2; ++c) {
          const int row = ar0 + c * 64;
          gl_lds16(W + (size_t)(n0 + row) * K + kk + ac, sB + half * sBh + (c * 4 + w) * 512);
        }
      } else {
        gl_lds16(W + (size_t)(n0 + ar0) * K + kk + ac, sB + half * sBh + w * 512);
      }
    }
    __syncthreads();

    #pragma unroll
    for (int half = 0; half < 2; ++half) {
      short8 af[MI], bf[NI];
      #pragma unroll
      for (int mi = 0; mi < MI; ++mi)
        af[mi] = *(const short8*)&sA[half * sAh + (wrow0 + mi * 16 + l16) * BK + quad * 8];
      #pragma unroll
      for (int ni = 0; ni < NI; ++ni)
        bf[ni] = *(const short8*)&sB[half * sBh + (wcol0 + ni * 16 + l16) * BK + quad * 8];
      #pragma unroll
      for (int mi = 0; mi < MI; ++mi)
        #pragma unroll
        for (int ni = 0; ni < NI; ++ni)
          acc[mi][ni] = __builtin_amdgcn_mfma_f32_16x16x32_bf16(af[mi], bf[ni], acc[mi][ni], 0, 0, 0);
    }
  }

  #pragma unroll
  for (int ni = 0; ni < NI; ++ni) {
    const int col = n0 + wcol0 + ni * 16 + l16;
    const float bvv = bias[col];
    #pragma unroll
    for (int mi = 0; mi < MI; ++mi) {
      const int row0 = m0 + wrow0 + mi * 16 + quad * 4;
      #pragma unroll
      for (int i = 0; i < 4; ++i) {
        float v = acc[mi][ni][i] + bvv;
        if (RELU) v = fmaxf(v, 0.f);
        C[(size_t)(row0 + i) * Nd + col] = f2b(v);
      }
    }
  }
}

// 1-D grid, XCD-chunk swizzle, y-FASTEST decomposition: consecutive flat ids
// share the same A row-panel -> A re-reads become L2 hits on one XCD instead
// of L3 re-fetches spread over 8 XCDs.
template<int BN, bool RELU, int NY>
__global__ __launch_bounds__(256) void gemm_tile(
    const unsigned short* __restrict__ A, const unsigned short* __restrict__ W,
    const float* __restrict__ bias,
    unsigned short* __restrict__ C, int M, int Nd, int K, int lda)
{
  __shared__ unsigned short sA[2 * 128 * 32];
  __shared__ unsigned short sB[2 * BN * 32];
  const int f  = xcd_swz(blockIdx.x, gridDim.x);
  const int bx = f / NY, by = f % NY;
  gemm_body<BN, RELU>(A, W, bias, C, Nd, K, lda,
                      bx * 128, by * BN, sA, sB);
}

// -------- BM=64 x BN=64 GEMM for the skinny Nd=256 layers (Wo, FF2) --------
// 1024 blocks = 4/CU = 4 waves/SIMD (vs 2 at BM=128): the short K-loops are
// barrier/latency-bound, so TLP is the binding resource, not MFMA density.
// Wave w: rows w*16 (MI=1), all 64 cols (NI=4). LDS 16 KB. Swizzled, y-fast.
template<bool RELU, int NY>
__global__ __launch_bounds__(256) void gemm_tile64(
    const unsigned short* __restrict__ A, const unsigned short* __restrict__ W,
    const float* __restrict__ bias,
    unsigned short* __restrict__ C, int M, int Nd, int K, int lda)
{
  constexpr int BK = 32;
  constexpr int sh = 64 * BK;                 // 2048 shorts per half
  __shared__ unsigned short sA[2 * sh];       // 8 KB
  __shared__ unsigned short sB[2 * sh];       // 8 KB

  const int t    = threadIdx.x;
  const int w    = t >> 6;
  const int lane = t & 63;
  const int quad = lane >> 4;
  const int l16  = lane & 15;
  const int f  = xcd_swz(blockIdx.x, gridDim.x);
  const int m0 = (f / NY) * 64;
  const int n0 = (f % NY) * 64;

  const int aflat = t * 8;                    // 256 thr x 16B = one 64x32 tile
  const int ar = aflat >> 5, ac = aflat & 31;

  floatx4 acc[4] = {};

  for (int k0 = 0; k0 < K; k0 += 2 * BK) {
    __syncthreads();
    #pragma unroll
    for (int half = 0; half < 2; ++half) {
      const int kk = k0 + half * BK;
      gl_lds16(A + (size_t)(m0 + ar) * lda + kk + ac, &sA[half * sh + aflat]);
      gl_lds16(W + (size_t)(n0 + ar) * K + kk + ac, &sB[half * sh + aflat]);
    }
    __syncthreads();
    #pragma unroll
    for (int half = 0; half < 2; ++half) {
      const short8 af = *(const short8*)&sA[half * sh + (w * 16 + l16) * BK + quad * 8];
      #pragma unroll
      for (int ni = 0; ni < 4; ++ni) {
        const short8 bf = *(const short8*)&sB[half * sh + (ni * 16 + l16) * BK + quad * 8];
        acc[ni] = __builtin_amdgcn_mfma_f32_16x16x32_bf16(af, bf, acc[ni], 0, 0, 0);
      }
    }
  }

  #pragma unroll
  for (int ni = 0; ni < 4; ++ni) {
    const int col = n0 + ni * 16 + l16;
    const float bvv = bias[col];
    const int row0 = m0 + w * 16 + quad * 4;
    #pragma unroll
    for (int i = 0; i < 4; ++i) {
      float v = acc[ni][i] + bvv;
      if (RELU) v = fmaxf(v, 0.f);
      C[(size_t)(row0 + i) * Nd + col] = f2b(v);
    }
  }
}

// -------- merged Q-proj + KV-proj: 1024 blocks, swizzled, y-fastest ---------
// yy<4: q = tgt_b @ Wq^T + bq (BN=64); yy>=4: kv = mp_b @ Wkv^T + bkv (BN=128).
// y-fastest: the 8 blocks of one x run on one XCD -> tgt & mp tiles L2-reused.
__global__ __launch_bounds__(256) void gemm_qkv(
    const unsigned short* __restrict__ tgt_b, const unsigned short* __restrict__ Wq_b,
    const float* __restrict__ bq, unsigned short* __restrict__ q_b,
    const unsigned short* __restrict__ mp_b, const unsigned short* __restrict__ Wkv_b,
    const float* __restrict__ bias_kv, unsigned short* __restrict__ kv_b)
{
  __shared__ unsigned short sA[2 * 128 * 32];
  __shared__ unsigned short sB[2 * 128 * 32];
  const int f  = xcd_swz(blockIdx.x, 1024);
  const int bx = f >> 3, yy = f & 7;
  const int m0 = bx * 128;
  if (yy < 4)
    gemm_body<64, false>(tgt_b, Wq_b, bq, q_b, 256, 256, 256,
                         m0, yy * 64, sA, sB);
  else
    gemm_body<128, false>(mp_b, Wkv_b, bias_kv, kv_b, 512, 512, 512,
                          m0, (yy - 4) * 128, sA, sB);
}

// -------- local gather attention: 1 block / query, kv bf16, direct gather ---
// Round-9 form (42 µs measured): UNCONDITIONAL batched gathers (clamped
// offsets), mask applied only at the score write. Guarding the loads was
// measured at +16 µs (round 10) — conditional loads serialize behind the
// branch and lose the TLP latency hiding. Do not re-guard.
// XCD swizzle: n = (blk&7)*2048 + blk>>3 -> per-XCD kv working set ~2MB in L2.
__global__ __launch_bounds__(256) void attn_kernel(
    const unsigned short* __restrict__ q, const unsigned short* __restrict__ kv,
    const int* __restrict__ key_batch_cnt, const int* __restrict__ index_pair,
    const int* __restrict__ index_pair_batch,
    unsigned short* __restrict__ out)
{
  const int n = ((blockIdx.x & 7) << 11) | (blockIdx.x >> 3);
  const int t = threadIdx.x;
  __shared__ unsigned short s_qb[DM];
#if !HAS_DOT2
  __shared__ float s_qf[DM];
#endif
  __shared__ int   s_gidx[LNEI];   // -1 = padded neighbor (mask)
  __shared__ int   s_goff[LNEI];   // clamped byte offset, 1024 B/row
  __shared__ float s_score[NH][LNEI];
  __shared__ float s_prob[NH][LNEI];
  __shared__ float s_out[2][DM];

  const unsigned short qr = q[(size_t)n * DM + t];
  s_qb[t] = qr;
#if !HAS_DOT2
  s_qf[t] = b2f(qr);
#endif
  if (t < 64) {                       // wave 0: offsets + gather indices
    const int b = index_pair_batch[n];              // uniform across wave
    int cnt = (t < 16) ? key_batch_cnt[t] : 0;      // one parallel load
    cnt = (t < b) ? cnt : 0;
    #pragma unroll
    for (int msk = 32; msk >= 1; msk >>= 1) cnt += __shfl_xor(cnt, msk, 64);
    if (t < LNEI) {
      const int ip = index_pair[(size_t)n * LNEI + t];
      const int gi = (ip < 0) ? -1 : (ip + cnt);
      s_gidx[t] = gi;
      s_goff[t] = (gi < 0 ? 0 : gi) << 10;
    }
  }
  __syncthreads();

  // Phase A (coalesced QK): t=(j=t>>3, c8=t&7)
  {
    const int j  = t >> 3;
    const int c8 = t & 7;
    const int g  = s_gidx[j];
    const char* kbase = (const char*)kv + s_goff[j];

    float part[4];
    #pragma unroll
    for (int i = 0; i < 4; ++i) {
      const int c = c8 + i * 8;                       // 16B chunk, 0..31
      const uint4_t d = *(const uint4_t*)(kbase + c * 16);
#if HAS_DOT2
      union { uint4_t u; bf16x2_t p[4]; } ku, qu;
      ku.u = d;
      qu.u = *(const uint4_t*)&s_qb[c * 8];
      float acc = 0.f;
      #pragma unroll
      for (int r = 0; r < 4; ++r)
        acc = __builtin_amdgcn_fdot2_f32_bf16(ku.p[r], qu.p[r], acc, false);
      part[i] = acc;
#else
      const float* qp = &s_qf[c * 8];
      part[i] = lo16(d.x) * qp[0] + hi16(d.x) * qp[1]
              + lo16(d.y) * qp[2] + hi16(d.y) * qp[3]
              + lo16(d.z) * qp[4] + hi16(d.z) * qp[5]
              + lo16(d.w) * qp[6] + hi16(d.w) * qp[7];
#endif
    }
    #pragma unroll
    for (int i = 0; i < 4; ++i) {
      part[i] += __shfl_xor(part[i], 1, 64);
      part[i] += __shfl_xor(part[i], 2, 64);
    }
    if ((c8 & 3) == 0) {
      const int hodd = c8 >> 2;
      #pragma unroll
      for (int i = 0; i < 4; ++i)
        s_score[2 * i + hodd][j] =
            (g < 0) ? -1e9f : part[i] * 0.17677669529663687f;  // 32^-0.5
    }
  }
  __syncthreads();

  // softmax: t = (h, l)
  {
    const int h = t >> 5;
    const int l = t & 31;
    const float sc = s_score[h][l];
    float mx = sc;
    #pragma unroll
    for (int msk = 16; msk >= 1; msk >>= 1) mx = fmaxf(mx, __shfl_xor(mx, msk, 64));
    const float e = __expf(sc - mx);
    float sm = e;
    #pragma unroll
    for (int msk = 16; msk >= 1; msk >>= 1) sm += __shfl_xor(sm, msk, 64);
    s_prob[h][l] = e / sm;
  }
  __syncthreads();

  // Phase B: t=(jh,h,dh2)
  {
    const int jh  = t >> 7;
    const int h   = (t >> 4) & 7;
    const int dh2 = t & 15;
    floatx4 p4[4];
    intx4   o4[4];
    #pragma unroll
    for (int r = 0; r < 4; ++r) {
      p4[r] = *(const floatx4*)&s_prob[h][jh * 16 + r * 4];
      o4[r] = *(const intx4*)&s_goff[jh * 16 + r * 4];
    }
    float2_t acc = {0.f, 0.f};
    const char* vbase = (const char*)kv + 512 + h * 64 + dh2 * 4;
    #pragma unroll
    for (int j2 = 0; j2 < 16; ++j2) {
      const int off = o4[j2 >> 2][j2 & 3];
      const float p = p4[j2 >> 2][j2 & 3];
      const unsigned int d = *(const unsigned int*)(vbase + off);
      acc = __builtin_elementwise_fma((float2_t){p, p},
                                      (float2_t){lo16(d), hi16(d)}, acc);
    }
    s_out[jh][h * DH + dh2 * 2]     = acc[0];
    s_out[jh][h * DH + dh2 * 2 + 1] = acc[1];
  }
  __syncthreads();

  out[(size_t)n * DM + t] = f2b(s_out[0][t] + s_out[1][t]);
}

// -------- residual + LayerNorm: 1 wave per row, 4 elems/lane, no LDS --------
template<bool IN1F32, bool OUTF32>
__global__ __launch_bounds__(256) void ln_kernel(
    const void* __restrict__ in1, const unsigned short* __restrict__ in2,
    const float* __restrict__ g, const float* __restrict__ b,
    void* __restrict__ out)
{
  const int n    = blockIdx.x * 4 + (threadIdx.x >> 6);
  const int lane = threadIdx.x & 63;
  const int c0   = lane * 4;

  float a[4];
  if (IN1F32) {
    const floatx4 v = *(const floatx4*)((const float*)in1 + (size_t)n * DM + c0);
    a[0] = v[0]; a[1] = v[1]; a[2] = v[2]; a[3] = v[3];
  } else {
    const ushort4_t u = *(const ushort4_t*)((const unsigned short*)in1 + (size_t)n * DM + c0);
    a[0] = b2f(u.x); a[1] = b2f(u.y); a[2] = b2f(u.z); a[3] = b2f(u.w);
  }
  {
    const ushort4_t u = *(const ushort4_t*)(in2 + (size_t)n * DM + c0);
    a[0] += b2f(u.x); a[1] += b2f(u.y); a[2] += b2f(u.z); a[3] += b2f(u.w);
  }

  float s = a[0] + a[1] + a[2] + a[3];
  #pragma unroll
  for (int msk = 32; msk >= 1; msk >>= 1) s += __shfl_xor(s, msk, 64);
  const float mean = s * (1.0f / DM);

  float d[4], s2 = 0.f;
  #pragma unroll
  for (int i = 0; i < 4; ++i) { d[i] = a[i] - mean; s2 += d[i] * d[i]; }
  #pragma unroll
  for (int msk = 32; msk >= 1; msk >>= 1) s2 += __shfl_xor(s2, msk, 64);
  const float r = rsqrtf(s2 * (1.0f / DM) + 1e-5f);

  const floatx4 gv = *(const floatx4*)(g + c0);
  const floatx4 bv = *(const floatx4*)(b + c0);
  if (OUTF32) {
    floatx4 y;
    #pragma unroll
    for (int i = 0; i < 4; ++i) y[i] = d[i] * r * gv[i] + bv[i];
    *((floatx4*)((float*)out + (size_t)n * DM + c0)) = y;
  } else {
    ushort4_t y;
    y.x = f2b(d[0] * r * gv[0] + bv[0]);
    y.y = f2b(d[1] * r * gv[1] + bv[1]);
    y.z = f2b(d[2] * r * gv[2] + bv[2]);
    y.w = f2b(d[3] * r * gv[3] + bv[3]);
    *((ushort4_t*)((unsigned short*)out + (size_t)n * DM + c0)) = y;
  }
}

extern "C" void kernel_launch(void* const* d_in, const int* in_sizes, int n_in,
                              void* d_out, int out_size, void* d_ws, size_t ws_size,
                              hipStream_t stream) {
  const float* tgt  = (const float*)d_in[0];
  const float* mem  = (const float*)d_in[1];
  const float* pos  = (const float*)d_in[2];
  const int* kbc    = (const int*)d_in[3];
  const int* ipair  = (const int*)d_in[4];
  const int* ipb    = (const int*)d_in[5];
  const float* Wq   = (const float*)d_in[6];
  const float* bq   = (const float*)d_in[7];
  const float* Wkc  = (const float*)d_in[8];
  const float* bkc  = (const float*)d_in[9];
  const float* Wkp  = (const float*)d_in[10];
  const float* bkp  = (const float*)d_in[11];
  const float* Wv   = (const float*)d_in[12];
  const float* bvp  = (const float*)d_in[13];
  const float* Wo   = (const float*)d_in[14];
  const float* bo   = (const float*)d_in[15];
  const float* W1   = (const float*)d_in[16];
  const float* b1   = (const float*)d_in[17];
  const float* W2   = (const float*)d_in[18];
  const float* b2   = (const float*)d_in[19];
  const float* g2   = (const float*)d_in[20];
  const float* be2  = (const float*)d_in[21];
  const float* g3   = (const float*)d_in[22];
  const float* be3  = (const float*)d_in[23];

  const size_t NB = (size_t)N_TOT * DM;
  unsigned short* ws = (unsigned short*)d_ws;
  unsigned short* tgt_b = ws;
  unsigned short* ao_b  = ws;
  unsigned short* t2_b  = ws + NB;
  unsigned short* mp_b  = ws + 2 * NB;
  unsigned short* x_b   = ws + 2 * NB;
  unsigned short* ff_b  = ws + 3 * NB;
  unsigned short* q_b   = ws + 4 * NB;
  unsigned short* h1_b  = ws + 4 * NB;
  unsigned short* kv_b  = ws + 5 * NB;
  unsigned short* wgt   = ws + 8 * NB;
  unsigned short* Wq_b  = wgt;
  unsigned short* Wkv_b = wgt + 65536;
  unsigned short* Wo_b  = wgt + 65536 + 262144;
  unsigned short* W1_b  = wgt + 2 * 65536 + 262144;
  unsigned short* W2_b  = wgt + 2 * 65536 + 2 * 262144;
  float* bias_kv = (float*)(wgt + 2 * 65536 + 3 * 262144);

  SegTable T;
  int beg = 0, i = 0;
  auto seg = [&](const float* s, unsigned short* d, int cols, int ostride, int ooff, int nelem) {
    T.s[i].src = s; T.s[i].dst = d; T.s[i].cols = cols;
    T.s[i].ostride = ostride; T.s[i].ooff = ooff; T.s[i].begin = beg;
    beg += nelem; ++i;
  };
  seg(tgt, tgt_b, DM, DM, 0,   (int)NB);
  seg(mem, mp_b,  DM, 512, 0,  (int)NB);
  seg(pos, mp_b,  DM, 512, DM, (int)NB);
  seg(Wq,  Wq_b,  DM, DM, 0,   65536);
  seg(Wkc, Wkv_b, DM, 512, 0,  65536);
  seg(Wkp, Wkv_b, DM, 512, DM, 65536);
  seg(Wv,  Wkv_b + (size_t)256 * 512, DM, 512, 0, 65536);
  seg(nullptr, Wkv_b + (size_t)256 * 512, DM, 512, DM, 65536);
  seg(Wo,  Wo_b,  DM, DM, 0,   65536);
  seg(W1,  W1_b,  DM, DM, 0,   262144);
  seg(W2,  W2_b,  DFF, DFF, 0, 262144);
  T.total = beg;

  dim3 blk(256);
  cvt_all<<<dim3(T.total / 1024 + 1), blk, 0, stream>>>(T, bias_kv, bkc, bkp, bvp);

  gemm_qkv<<<dim3(1024), blk, 0, stream>>>(tgt_b, Wq_b, bq, q_b, mp_b, Wkv_b, bias_kv, kv_b);
  attn_kernel<<<dim3(N_TOT), blk, 0, stream>>>(q_b, kv_b, kbc, ipair, ipb, ao_b);
  gemm_tile64<false, 4><<<dim3(1024), blk, 0, stream>>>(ao_b, Wo_b, bo, t2_b, N_TOT, DM, DM, DM);
  ln_kernel<true, false><<<dim3(N_TOT / 4), blk, 0, stream>>>(tgt, t2_b, g2, be2, x_b);
  gemm_tile<128, true, 8><<<dim3(1024), blk, 0, stream>>>(x_b, W1_b, b1, h1_b, N_TOT, DFF, DM, DM);
  gemm_tile64<false, 4><<<dim3(1024), blk, 0, stream>>>(h1_b, W2_b, b2, ff_b, N_TOT, DM, DFF, DFF);
  ln_kernel<false, true><<<dim3(N_TOT / 4), blk, 0, stream>>>(x_b, ff_b, g3, be3, d_out);
}